// Round 1
// baseline (1053.453 us; speedup 1.0000x reference)
//
#include <hip/hip_runtime.h>
#include <math.h>

#define N_NODES 50000
#define N_EDGES 800000
#define IN_DIM 128
#define OUT_DIM 16
#define N_HEADS 4
#define HID 64            // N_HEADS*OUT_DIM
#define AW_COLS 33        // 2*OUT_DIM+1

// --- ordered-uint encoding for fp32 atomic max (init value 0 == -NaN, below all reals)
__device__ __forceinline__ unsigned int ord_of_float(float f) {
    unsigned u = __float_as_uint(f);
    return (u & 0x80000000u) ? ~u : (u | 0x80000000u);
}
__device__ __forceinline__ float float_of_ord(unsigned u) {
    unsigned v = (u & 0x80000000u) ? (u & 0x7fffffffu) : ~u;
    return __uint_as_float(v);
}

// h = nodes @ W.T + b  (fp64 accumulate). Block = 256 threads = 4 nodes x 64 outputs.
__global__ __launch_bounds__(256) void gemm_h(const float* __restrict__ nodes,
                                              const float* __restrict__ W,
                                              const float* __restrict__ b,
                                              float* __restrict__ h) {
    __shared__ float sW[HID * (IN_DIM + 1)];   // +1 pad: conflict-free column reads
    __shared__ float sN[4 * IN_DIM];
    int t = threadIdx.x;
    for (int i = t; i < HID * IN_DIM; i += 256) {
        int o = i / IN_DIM, k = i % IN_DIM;
        sW[o * (IN_DIM + 1) + k] = W[i];
    }
    int node0 = blockIdx.x * 4;
    for (int i = t; i < 4 * IN_DIM; i += 256) {
        int n = node0 + i / IN_DIM;
        sN[i] = (n < N_NODES) ? nodes[(long long)n * IN_DIM + (i % IN_DIM)] : 0.f;
    }
    __syncthreads();
    int ln = t >> 6;   // wave index -> local node (wave-uniform)
    int o  = t & 63;
    int n = node0 + ln;
    if (n >= N_NODES) return;
    double acc = (double)b[o];
    const float* wr = &sW[o * (IN_DIM + 1)];
    const float* nr = &sN[ln * IN_DIM];
    #pragma unroll 8
    for (int k = 0; k < IN_DIM; ++k)
        acc += (double)nr[k] * (double)wr[k];
    h[(long long)n * HID + o] = (float)acc;
}

// Pass 1: per (edge, head): y = leaky(dot(feat, attn_W)+attn_b); atomicMax segment max;
// block-reduced double sum of edges[sender] (counted once per edge) for S.
__global__ __launch_bounds__(256) void edge_logits(
    const float* __restrict__ h, const float* __restrict__ edges,
    const int* __restrict__ senders, const int* __restrict__ receivers,
    const float* __restrict__ attn_W, const float* __restrict__ attn_b,
    float* __restrict__ yw, unsigned int* __restrict__ m_ord,
    double* __restrict__ Ssum) {
    __shared__ double sAW[N_HEADS][AW_COLS];
    __shared__ double sAb[N_HEADS];
    __shared__ double red[256];
    int t = threadIdx.x;
    if (t < N_HEADS * AW_COLS) sAW[t / AW_COLS][t % AW_COLS] = (double)attn_W[t];
    if (t < N_HEADS) sAb[t] = (double)attn_b[t];
    __syncthreads();
    long long gid = (long long)blockIdx.x * 256 + t;
    double sp = 0.0;
    if (gid < (long long)N_EDGES * N_HEADS) {
        int e  = (int)(gid >> 2);
        int hd = (int)(gid & 3);
        int s = senders[e], r = receivers[e];
        const float4* hs4 = (const float4*)(h + (long long)s * HID + hd * OUT_DIM);
        const float4* hr4 = (const float4*)(h + (long long)r * HID + hd * OUT_DIM);
        double acc = sAb[hd];
        #pragma unroll
        for (int q = 0; q < 4; ++q) {
            float4 a = hs4[q];
            float4 c = hr4[q];
            const double* ws = &sAW[hd][4 * q];
            const double* wr = &sAW[hd][OUT_DIM + 4 * q];
            acc += (double)a.x * ws[0] + (double)a.y * ws[1] +
                   (double)a.z * ws[2] + (double)a.w * ws[3];
            acc += (double)c.x * wr[0] + (double)c.y * wr[1] +
                   (double)c.z * wr[2] + (double)c.w * wr[3];
        }
        float se = edges[s];
        acc += (double)se * sAW[hd][2 * OUT_DIM];
        double y = acc > 0.0 ? acc : 0.01 * acc;
        float yf = (float)y;
        yw[gid] = yf;
        atomicMax(&m_ord[(long long)r * N_HEADS + hd], ord_of_float(yf));
        if (hd == 0) sp = (double)se;
    }
    red[t] = sp;
    __syncthreads();
    for (int off = 128; off > 0; off >>= 1) {
        if (t < off) red[t] += red[t + off];
        __syncthreads();
    }
    if (t == 0) atomicAdd(Ssum, red[0]);
}

// Pass 2: per (edge, head, 4-elem group): e = exp(S*(y-m)); accumulate denominator
// and unnormalized messages (atomic fp32).
__global__ __launch_bounds__(256) void edge_scatter(
    const float* __restrict__ h, const float* __restrict__ yw,
    const int* __restrict__ senders, const int* __restrict__ receivers,
    const unsigned int* __restrict__ m_ord, const double* __restrict__ Ssum,
    float* __restrict__ s_den, float* __restrict__ out_acc) {
    long long gid = (long long)blockIdx.x * 256 + threadIdx.x;
    if (gid >= (long long)N_EDGES * 16) return;
    int e   = (int)(gid >> 4);
    int rem = (int)(gid & 15);
    int hd = rem >> 2, g = rem & 3;
    int snd = senders[e], r = receivers[e];
    float yf = yw[(long long)e * N_HEADS + hd];
    float mf = float_of_ord(m_ord[(long long)r * N_HEADS + hd]);
    double S = 4.0 * Ssum[0];                      // sent_e tiled over heads
    double arg = S * ((double)yf - (double)mf);    // exact fp32 diff in double
    float ev = (float)exp(arg);                    // arg <= 0 always
    if (g == 0) atomicAdd(&s_den[(long long)r * N_HEADS + hd], ev);
    const float4 sv = *(const float4*)(h + (long long)snd * HID + hd * OUT_DIM + g * 4);
    float* op = out_acc + (long long)r * HID + hd * OUT_DIM + g * 4;
    atomicAdd(op + 0, ev * sv.x);
    atomicAdd(op + 1, ev * sv.y);
    atomicAdd(op + 2, ev * sv.z);
    atomicAdd(op + 3, ev * sv.w);
}

// Pass 3: out = leaky_relu(acc / s)
__global__ __launch_bounds__(256) void finalize(const float* __restrict__ s_den,
                                                float* __restrict__ out) {
    int i = blockIdx.x * 256 + threadIdx.x;
    if (i >= N_NODES * HID) return;
    int n = i / HID;
    int hd = (i % HID) / OUT_DIM;
    float s = s_den[n * N_HEADS + hd];
    float v = out[i];
    float r = (s > 0.f) ? v / s : 0.f;
    out[i] = r > 0.f ? r : 0.01f * r;
}

extern "C" void kernel_launch(void* const* d_in, const int* in_sizes, int n_in,
                              void* d_out, int out_size, void* d_ws, size_t ws_size,
                              hipStream_t stream) {
    const float* nodes     = (const float*)d_in[0];
    const float* edges     = (const float*)d_in[1];
    const int*   senders   = (const int*)d_in[2];
    const int*   receivers = (const int*)d_in[3];
    const float* W         = (const float*)d_in[4];
    const float* b         = (const float*)d_in[5];
    const float* attn_W    = (const float*)d_in[6];
    const float* attn_b    = (const float*)d_in[7];
    float* out = (float*)d_out;

    char* ws = (char*)d_ws;
    float* h = (float*)ws;                    ws += sizeof(float) * N_NODES * HID;
    float* yw = (float*)ws;                   ws += sizeof(float) * (size_t)N_EDGES * N_HEADS;
    unsigned int* m_ord = (unsigned int*)ws;  ws += sizeof(unsigned) * N_NODES * N_HEADS;
    float* s_den = (float*)ws;                ws += sizeof(float) * N_NODES * N_HEADS;
    double* Ssum = (double*)ws;               ws += sizeof(double);

    hipMemsetAsync(m_ord, 0, sizeof(unsigned) * N_NODES * N_HEADS, stream);
    hipMemsetAsync(s_den, 0, sizeof(float) * N_NODES * N_HEADS, stream);
    hipMemsetAsync(Ssum, 0, sizeof(double), stream);
    hipMemsetAsync(d_out, 0, sizeof(float) * N_NODES * HID, stream);

    gemm_h<<<(N_NODES + 3) / 4, 256, 0, stream>>>(nodes, W, b, h);
    edge_logits<<<(int)(((long long)N_EDGES * N_HEADS + 255) / 256), 256, 0, stream>>>(
        h, edges, senders, receivers, attn_W, attn_b, yw, m_ord, Ssum);
    edge_scatter<<<(int)(((long long)N_EDGES * 16 + 255) / 256), 256, 0, stream>>>(
        h, yw, senders, receivers, m_ord, Ssum, s_den, out);
    finalize<<<(N_NODES * HID + 255) / 256, 256, 0, stream>>>(s_den, out);
}

// Round 3
// 605.256 us; speedup vs baseline: 1.7405x; 1.7405x over previous
//
#include <hip/hip_runtime.h>
#include <math.h>
#include <stdint.h>

#define N_NODES 50000
#define N_EDGES 800000
#define IN_DIM 128
#define OUT_DIM 16
#define N_HEADS 4
#define HID 64            // N_HEADS*OUT_DIM
#define AW_COLS 33        // 2*OUT_DIM+1
#define SCAN_T 1024
#define SCAN_CH ((N_NODES + SCAN_T - 1) / SCAN_T)   // 49

// --- ordered-uint encoding for fp32 atomic max (init 0 sorts below all reals)
__device__ __forceinline__ unsigned int ord_of_float(float f) {
    unsigned u = __float_as_uint(f);
    return (u & 0x80000000u) ? ~u : (u | 0x80000000u);
}
__device__ __forceinline__ float float_of_ord(unsigned u) {
    unsigned v = (u & 0x80000000u) ? (u & 0x7fffffffu) : ~u;
    return __uint_as_float(v);
}

// h = nodes @ W.T + b  (fp64 accumulate). Block = 256 threads = 4 nodes x 64 outputs.
__global__ __launch_bounds__(256) void gemm_h(const float* __restrict__ nodes,
                                              const float* __restrict__ W,
                                              const float* __restrict__ b,
                                              float* __restrict__ h) {
    __shared__ float sW[HID * (IN_DIM + 1)];
    __shared__ float sN[4 * IN_DIM];
    int t = threadIdx.x;
    for (int i = t; i < HID * IN_DIM; i += 256) {
        int o = i / IN_DIM, k = i % IN_DIM;
        sW[o * (IN_DIM + 1) + k] = W[i];
    }
    int node0 = blockIdx.x * 4;
    for (int i = t; i < 4 * IN_DIM; i += 256) {
        int n = node0 + i / IN_DIM;
        sN[i] = (n < N_NODES) ? nodes[(long long)n * IN_DIM + (i % IN_DIM)] : 0.f;
    }
    __syncthreads();
    int ln = t >> 6;
    int o  = t & 63;
    int n = node0 + ln;
    if (n >= N_NODES) return;
    double acc = (double)b[o];
    const float* wr = &sW[o * (IN_DIM + 1)];
    const float* nr = &sN[ln * IN_DIM];
    #pragma unroll 8
    for (int k = 0; k < IN_DIM; ++k)
        acc += (double)nr[k] * (double)wr[k];
    h[(long long)n * HID + o] = (float)acc;
}

// Pass 1: per (edge, head): y = leaky(dot(feat, attn_W)+attn_b) -> yw;
// atomicMax segment max; receiver histogram; block-reduced double sum for S.
__global__ __launch_bounds__(256) void edge_logits(
    const float* __restrict__ h, const float* __restrict__ edges,
    const int* __restrict__ senders, const int* __restrict__ receivers,
    const float* __restrict__ attn_W, const float* __restrict__ attn_b,
    float* __restrict__ yw, unsigned int* __restrict__ m_ord,
    int* __restrict__ counts, double* __restrict__ Ssum) {
    __shared__ double sAW[N_HEADS][AW_COLS];
    __shared__ double sAb[N_HEADS];
    __shared__ double red[256];
    int t = threadIdx.x;
    if (t < N_HEADS * AW_COLS) sAW[t / AW_COLS][t % AW_COLS] = (double)attn_W[t];
    if (t < N_HEADS) sAb[t] = (double)attn_b[t];
    __syncthreads();
    long long gid = (long long)blockIdx.x * 256 + t;
    double sp = 0.0;
    if (gid < (long long)N_EDGES * N_HEADS) {
        int e  = (int)(gid >> 2);
        int hd = (int)(gid & 3);
        int s = senders[e], r = receivers[e];
        const float4* hs4 = (const float4*)(h + (long long)s * HID + hd * OUT_DIM);
        const float4* hr4 = (const float4*)(h + (long long)r * HID + hd * OUT_DIM);
        double acc = sAb[hd];
        #pragma unroll
        for (int q = 0; q < 4; ++q) {
            float4 a = hs4[q];
            float4 c = hr4[q];
            const double* ws = &sAW[hd][4 * q];
            const double* wrp = &sAW[hd][OUT_DIM + 4 * q];
            acc += (double)a.x * ws[0] + (double)a.y * ws[1] +
                   (double)a.z * ws[2] + (double)a.w * ws[3];
            acc += (double)c.x * wrp[0] + (double)c.y * wrp[1] +
                   (double)c.z * wrp[2] + (double)c.w * wrp[3];
        }
        float se = edges[s];
        acc += (double)se * sAW[hd][2 * OUT_DIM];
        double y = acc > 0.0 ? acc : 0.01 * acc;
        float yf = (float)y;
        yw[gid] = yf;
        atomicMax(&m_ord[(long long)r * N_HEADS + hd], ord_of_float(yf));
        if (hd == 0) {
            atomicAdd(&counts[r], 1);
            sp = (double)se;
        }
    }
    red[t] = sp;
    __syncthreads();
    for (int off = 128; off > 0; off >>= 1) {
        if (t < off) red[t] += red[t + off];
        __syncthreads();
    }
    if (t == 0) atomicAdd(Ssum, red[0]);
}

// Single-block exclusive scan of counts -> offsets[N+1], plus cursor rewrite.
// NOTE: cursor may alias counts — counts[i] is read into a local before the
// (possibly aliasing) cursor[i] write, and each i is owned by one thread.
__global__ __launch_bounds__(SCAN_T) void scan_counts(const int* __restrict__ counts,
                                                      int* __restrict__ offsets,
                                                      int* cursor) {
    __shared__ int ssum[SCAN_T];
    int t = threadIdx.x;
    int base = t * SCAN_CH;
    int local = 0;
    for (int i = base; i < base + SCAN_CH && i < N_NODES; ++i) local += counts[i];
    ssum[t] = local;
    __syncthreads();
    for (int off = 1; off < SCAN_T; off <<= 1) {
        int v = 0;
        if (t >= off) v = ssum[t - off];
        __syncthreads();
        ssum[t] += v;
        __syncthreads();
    }
    int running = ssum[t] - local;   // exclusive prefix of this chunk
    for (int i = base; i < base + SCAN_CH && i < N_NODES; ++i) {
        int c = counts[i];           // read BEFORE aliasing write
        offsets[i] = running;
        cursor[i] = running;
        running += c;
    }
    if (t == SCAN_T - 1) offsets[N_NODES] = ssum[SCAN_T - 1];
}

// Scatter edge ids into receiver-sorted order.
__global__ __launch_bounds__(256) void fill_perm(const int* __restrict__ receivers,
                                                 int* __restrict__ cursor,
                                                 int* __restrict__ perm) {
    int e = blockIdx.x * 256 + threadIdx.x;
    if (e >= N_EDGES) return;
    int r = receivers[e];
    int pos = atomicAdd(&cursor[r], 1);
    perm[pos] = e;
}

// In-place: yw -> exp(S * (yw - m[receiver]))
__global__ __launch_bounds__(256) void ev_inplace(float* __restrict__ yw,
                                                  const int* __restrict__ receivers,
                                                  const unsigned int* __restrict__ m_ord,
                                                  const double* __restrict__ Ssum) {
    long long gid = (long long)blockIdx.x * 256 + threadIdx.x;
    if (gid >= (long long)N_EDGES * N_HEADS) return;
    int e = (int)(gid >> 2);
    int hd = (int)(gid & 3);
    int r = receivers[e];
    float mf = float_of_ord(m_ord[(long long)r * N_HEADS + hd]);
    double S = 4.0 * Ssum[0];                        // sent_e tiled over heads
    double arg = S * ((double)yw[gid] - (double)mf); // <= 0; max edge gives exactly 0
    yw[gid] = (float)exp(arg);
}

// One wave per node: lane = output element (hd = lane/16). Accumulate ev * h[sender]
// over the node's CSR edge list in fp64 registers; normalize; leaky; single write.
__global__ __launch_bounds__(256) void gather(
    const float* __restrict__ h, const float* __restrict__ ev,
    const int* __restrict__ senders, const int* __restrict__ perm,
    const int* __restrict__ offsets, float* __restrict__ out) {
    int node = blockIdx.x * 4 + (threadIdx.x >> 6);
    int lane = threadIdx.x & 63;
    if (node >= N_NODES) return;
    int hd = lane >> 4;
    int start = offsets[node];
    int end = offsets[node + 1];
    double acc = 0.0, den = 0.0;
    for (int j = start; j < end; ++j) {
        int e = perm[j];
        int snd = senders[e];
        float evv = ev[(long long)e * N_HEADS + hd];
        acc += (double)evv * (double)h[(long long)snd * HID + lane];
        den += (double)evv;
    }
    float r = (den > 0.0) ? (float)(acc / den) : 0.f;
    out[(long long)node * HID + lane] = r > 0.f ? r : 0.01f * r;
}

static inline char* ws_take(char*& p, size_t bytes) {
    char* cur = p;
    p += (bytes + 255) & ~(size_t)255;   // keep every buffer 256B-aligned
    return cur;
}

extern "C" void kernel_launch(void* const* d_in, const int* in_sizes, int n_in,
                              void* d_out, int out_size, void* d_ws, size_t ws_size,
                              hipStream_t stream) {
    const float* nodes     = (const float*)d_in[0];
    const float* edges     = (const float*)d_in[1];
    const int*   senders   = (const int*)d_in[2];
    const int*   receivers = (const int*)d_in[3];
    const float* W         = (const float*)d_in[4];
    const float* b         = (const float*)d_in[5];
    const float* attn_W    = (const float*)d_in[6];
    const float* attn_b    = (const float*)d_in[7];
    float* out = (float*)d_out;

    char* p = (char*)d_ws;
    float* h        = (float*)ws_take(p, sizeof(float) * N_NODES * HID);
    float* yw       = (float*)ws_take(p, sizeof(float) * (size_t)N_EDGES * N_HEADS);
    unsigned* m_ord = (unsigned*)ws_take(p, sizeof(unsigned) * N_NODES * N_HEADS);
    int* counts     = (int*)ws_take(p, sizeof(int) * N_NODES);   // reused as cursor
    int* offsets    = (int*)ws_take(p, sizeof(int) * (N_NODES + 1));
    int* perm       = (int*)ws_take(p, sizeof(int) * (size_t)N_EDGES);
    double* Ssum    = (double*)ws_take(p, sizeof(double));
    int* cursor = counts;   // alias: scan_counts rewrites counts into cursor values

    hipMemsetAsync(m_ord, 0, sizeof(unsigned) * N_NODES * N_HEADS, stream);
    hipMemsetAsync(counts, 0, sizeof(int) * N_NODES, stream);
    hipMemsetAsync(Ssum, 0, sizeof(double), stream);

    gemm_h<<<(N_NODES + 3) / 4, 256, 0, stream>>>(nodes, W, b, h);
    edge_logits<<<(int)(((long long)N_EDGES * N_HEADS + 255) / 256), 256, 0, stream>>>(
        h, edges, senders, receivers, attn_W, attn_b, yw, m_ord, counts, Ssum);
    scan_counts<<<1, SCAN_T, 0, stream>>>(counts, offsets, cursor);
    fill_perm<<<(N_EDGES + 255) / 256, 256, 0, stream>>>(receivers, cursor, perm);
    ev_inplace<<<(int)(((long long)N_EDGES * N_HEADS + 255) / 256), 256, 0, stream>>>(
        yw, receivers, m_ord, Ssum);
    gather<<<(N_NODES + 3) / 4, 256, 0, stream>>>(h, yw, senders, perm, offsets, out);
}

// Round 4
// 475.127 us; speedup vs baseline: 2.2172x; 1.2739x over previous
//
#include <hip/hip_runtime.h>
#include <math.h>

#define N_NODES 50000
#define N_EDGES 800000
#define IN_DIM 128
#define OUT_DIM 16
#define N_HEADS 4
#define HID 64            // N_HEADS*OUT_DIM
#define AW_COLS 33        // 2*OUT_DIM+1
#define SCAN_T 1024
#define SCAN_CH ((N_NODES + SCAN_T - 1) / SCAN_T)   // 49

// h = nodes @ W.T + b  (fp64 accumulate). Block = 256 threads = 4 nodes x 64 outputs.
__global__ __launch_bounds__(256) void gemm_h(const float* __restrict__ nodes,
                                              const float* __restrict__ W,
                                              const float* __restrict__ b,
                                              float* __restrict__ h) {
    __shared__ float sW[HID * (IN_DIM + 1)];
    __shared__ float sN[4 * IN_DIM];
    int t = threadIdx.x;
    for (int i = t; i < HID * IN_DIM; i += 256) {
        int o = i / IN_DIM, k = i % IN_DIM;
        sW[o * (IN_DIM + 1) + k] = W[i];
    }
    int node0 = blockIdx.x * 4;
    for (int i = t; i < 4 * IN_DIM; i += 256) {
        int n = node0 + i / IN_DIM;
        sN[i] = (n < N_NODES) ? nodes[(long long)n * IN_DIM + (i % IN_DIM)] : 0.f;
    }
    __syncthreads();
    int ln = t >> 6;
    int o  = t & 63;
    int n = node0 + ln;
    if (n >= N_NODES) return;
    double acc = (double)b[o];
    const float* wr = &sW[o * (IN_DIM + 1)];
    const float* nr = &sN[ln * IN_DIM];
    #pragma unroll 8
    for (int k = 0; k < IN_DIM; ++k)
        acc += (double)nr[k] * (double)wr[k];
    h[(long long)n * HID + o] = (float)acc;
}

// Per (node, head): a_src = dot(h[n,hd,:], attn_W[hd][0:16]),
//                   a_dst = dot(h[n,hd,:], attn_W[hd][16:32])  (fp64).
__global__ __launch_bounds__(256) void alphas(const float* __restrict__ h,
                                              const float* __restrict__ attn_W,
                                              double* __restrict__ a_src,
                                              double* __restrict__ a_dst) {
    int gid = blockIdx.x * 256 + threadIdx.x;
    if (gid >= N_NODES * N_HEADS) return;
    int n = gid >> 2, c = gid & 3;
    const float* hp = h + (long long)n * HID + c * OUT_DIM;
    const float* ws = attn_W + c * AW_COLS;
    double s0 = 0.0, s1 = 0.0;
    #pragma unroll
    for (int d = 0; d < OUT_DIM; ++d) {
        double hv = (double)hp[d];
        s0 += hv * (double)ws[d];
        s1 += hv * (double)ws[OUT_DIM + d];
    }
    a_src[gid] = s0;
    a_dst[gid] = s1;
}

// Receiver histogram + block-reduced double sum of edges[sender] -> Ssum.
__global__ __launch_bounds__(256) void hist(const int* __restrict__ senders,
                                            const int* __restrict__ receivers,
                                            const float* __restrict__ edges,
                                            int* __restrict__ counts,
                                            double* __restrict__ Ssum) {
    __shared__ double red[256];
    int t = threadIdx.x;
    int e = blockIdx.x * 256 + t;
    double sp = 0.0;
    if (e < N_EDGES) {
        atomicAdd(&counts[receivers[e]], 1);
        sp = (double)edges[senders[e]];
    }
    red[t] = sp;
    __syncthreads();
    for (int off = 128; off > 0; off >>= 1) {
        if (t < off) red[t] += red[t + off];
        __syncthreads();
    }
    if (t == 0) atomicAdd(Ssum, red[0]);
}

// Single-block exclusive scan of counts -> offsets[N+1], plus cursor rewrite.
// cursor may alias counts (read-before-write, one owner thread per index).
__global__ __launch_bounds__(SCAN_T) void scan_counts(const int* __restrict__ counts,
                                                      int* __restrict__ offsets,
                                                      int* cursor) {
    __shared__ int ssum[SCAN_T];
    int t = threadIdx.x;
    int base = t * SCAN_CH;
    int local = 0;
    for (int i = base; i < base + SCAN_CH && i < N_NODES; ++i) local += counts[i];
    ssum[t] = local;
    __syncthreads();
    for (int off = 1; off < SCAN_T; off <<= 1) {
        int v = 0;
        if (t >= off) v = ssum[t - off];
        __syncthreads();
        ssum[t] += v;
        __syncthreads();
    }
    int running = ssum[t] - local;
    for (int i = base; i < base + SCAN_CH && i < N_NODES; ++i) {
        int c = counts[i];
        offsets[i] = running;
        cursor[i] = running;
        running += c;
    }
    if (t == SCAN_T - 1) offsets[N_NODES] = ssum[SCAN_T - 1];
}

// Scatter sender ids into receiver-sorted order (no perm needed downstream).
__global__ __launch_bounds__(256) void fill_srt(const int* __restrict__ senders,
                                                const int* __restrict__ receivers,
                                                int* __restrict__ cursor,
                                                int* __restrict__ srt_sender) {
    int e = blockIdx.x * 256 + threadIdx.x;
    if (e >= N_EDGES) return;
    int pos = atomicAdd(&cursor[receivers[e]], 1);
    srt_sender[pos] = senders[e];
}

// One wave per node: logits from alphas, wave-reduced max, ev, weighted gather,
// normalize + leaky. Online rescale across 64-edge chunks (any degree correct).
__global__ __launch_bounds__(256) void node_fused(
    const float* __restrict__ h, const double* __restrict__ a_src,
    const double* __restrict__ a_dst, const float* __restrict__ edges,
    const int* __restrict__ srt_sender, const int* __restrict__ offsets,
    const float* __restrict__ attn_W, const float* __restrict__ attn_b,
    const double* __restrict__ Ssum, float* __restrict__ out) {
    int node = blockIdx.x * 4 + (threadIdx.x >> 6);
    int lane = threadIdx.x & 63;
    if (node >= N_NODES) return;
    int hd = lane >> 4;
    int start = offsets[node], end = offsets[node + 1];
    long long obase = (long long)node * HID + lane;
    if (start >= end) { out[obase] = 0.f; return; }

    double S = 4.0 * Ssum[0];                    // sent_e tiled over heads
    double w4[4], b4[4], adst4[4];
    #pragma unroll
    for (int c = 0; c < 4; ++c) {
        w4[c] = (double)attn_W[c * AW_COLS + 2 * OUT_DIM];
        b4[c] = (double)attn_b[c];
        adst4[c] = a_dst[node * 4 + c];
    }
    float m_run[4] = {-INFINITY, -INFINITY, -INFINITY, -INFINITY};
    double den4[4] = {0.0, 0.0, 0.0, 0.0};
    double acc = 0.0;

    for (int cbase = start; cbase < end; cbase += 64) {
        int cd = end - cbase; if (cd > 64) cd = 64;
        bool active = lane < cd;
        int s = 0;
        float y4[4];
        if (active) {
            s = srt_sender[cbase + lane];
            double se = (double)edges[s];
            const double* as = a_src + (long long)s * 4;
            #pragma unroll
            for (int c = 0; c < 4; ++c) {
                double yy = as[c] + adst4[c] + se * w4[c] + b4[c];
                yy = yy > 0.0 ? yy : 0.01 * yy;   // leaky_relu (fp64, then round)
                y4[c] = (float)yy;
            }
        } else {
            y4[0] = y4[1] = y4[2] = y4[3] = -INFINITY;
        }
        // per-head chunk max across the wave
        #pragma unroll
        for (int c = 0; c < 4; ++c) {
            float v = y4[c];
            #pragma unroll
            for (int k = 32; k >= 1; k >>= 1)
                v = fmaxf(v, __shfl_xor(v, k, 64));
            float mn = fmaxf(m_run[c], v);
            if (mn > m_run[c]) {                 // wave-uniform condition
                double sc = (m_run[c] == -INFINITY) ? 0.0
                          : exp(S * ((double)m_run[c] - (double)mn));
                den4[c] *= sc;
                if (c == hd) acc *= sc;
                m_run[c] = mn;
            }
        }
        // per-lane ev for its edge (fp64 exp, fp32 store — matches prior rounds)
        float ev4[4];
        #pragma unroll
        for (int c = 0; c < 4; ++c)
            ev4[c] = active ? (float)exp(S * ((double)y4[c] - (double)m_run[c])) : 0.f;
        // denominator: per-head wave sums in fp64
        #pragma unroll
        for (int c = 0; c < 4; ++c) {
            double dv = (double)ev4[c];
            #pragma unroll
            for (int k = 32; k >= 1; k >>= 1)
                dv += __shfl_xor(dv, k, 64);
            den4[c] += dv;
        }
        // message accumulation: broadcast each edge's (s, ev) via shuffles;
        // skip edges whose ev underflowed to 0 in every head (exact skip).
        for (int j = 0; j < cd; ++j) {
            float e0 = __shfl(ev4[0], j, 64);
            float e1 = __shfl(ev4[1], j, 64);
            float e2 = __shfl(ev4[2], j, 64);
            float e3 = __shfl(ev4[3], j, 64);
            if (e0 == 0.f && e1 == 0.f && e2 == 0.f && e3 == 0.f) continue;
            int sj = __shfl(s, j, 64);
            float evv = hd == 0 ? e0 : hd == 1 ? e1 : hd == 2 ? e2 : e3;
            acc += (double)evv * (double)h[(long long)sj * HID + lane];
        }
    }
    double dn = den4[hd];
    float r = (dn > 0.0) ? (float)(acc / dn) : 0.f;
    out[obase] = r > 0.f ? r : 0.01f * r;
}

static inline char* ws_take(char*& p, size_t bytes) {
    char* cur = p;
    p += (bytes + 255) & ~(size_t)255;   // keep every buffer 256B-aligned
    return cur;
}

extern "C" void kernel_launch(void* const* d_in, const int* in_sizes, int n_in,
                              void* d_out, int out_size, void* d_ws, size_t ws_size,
                              hipStream_t stream) {
    const float* nodes     = (const float*)d_in[0];
    const float* edges     = (const float*)d_in[1];
    const int*   senders   = (const int*)d_in[2];
    const int*   receivers = (const int*)d_in[3];
    const float* W         = (const float*)d_in[4];
    const float* b         = (const float*)d_in[5];
    const float* attn_W    = (const float*)d_in[6];
    const float* attn_b    = (const float*)d_in[7];
    float* out = (float*)d_out;

    char* p = (char*)d_ws;
    float*  h          = (float*)ws_take(p, sizeof(float) * N_NODES * HID);
    double* a_src      = (double*)ws_take(p, sizeof(double) * N_NODES * N_HEADS);
    double* a_dst      = (double*)ws_take(p, sizeof(double) * N_NODES * N_HEADS);
    int*    counts     = (int*)ws_take(p, sizeof(int) * N_NODES);   // reused as cursor
    int*    offsets    = (int*)ws_take(p, sizeof(int) * (N_NODES + 1));
    int*    srt_sender = (int*)ws_take(p, sizeof(int) * (size_t)N_EDGES);
    double* Ssum       = (double*)ws_take(p, sizeof(double));
    int* cursor = counts;

    hipMemsetAsync(counts, 0, sizeof(int) * N_NODES, stream);
    hipMemsetAsync(Ssum, 0, sizeof(double), stream);

    gemm_h<<<(N_NODES + 3) / 4, 256, 0, stream>>>(nodes, W, b, h);
    alphas<<<(N_NODES * N_HEADS + 255) / 256, 256, 0, stream>>>(h, attn_W, a_src, a_dst);
    hist<<<(N_EDGES + 255) / 256, 256, 0, stream>>>(senders, receivers, edges, counts, Ssum);
    scan_counts<<<1, SCAN_T, 0, stream>>>(counts, offsets, cursor);
    fill_srt<<<(N_EDGES + 255) / 256, 256, 0, stream>>>(senders, receivers, cursor, srt_sender);
    node_fused<<<(N_NODES + 3) / 4, 256, 0, stream>>>(
        h, a_src, a_dst, edges, srt_sender, offsets, attn_W, attn_b, Ssum, out);
}

// Round 5
// 392.690 us; speedup vs baseline: 2.6827x; 1.2099x over previous
//
#include <hip/hip_runtime.h>
#include <math.h>

#define N_NODES 50000
#define N_EDGES 800000
#define IN_DIM 128
#define OUT_DIM 16
#define N_HEADS 4
#define HID 64            // N_HEADS*OUT_DIM
#define AW_COLS 33        // 2*OUT_DIM+1
#define SCAN_T 1024
#define SCAN_CH ((N_NODES + SCAN_T - 1) / SCAN_T)   // 49

// h = nodes @ W.T + b (fp64 accumulate, SAME k-order as prior rounds) fused with
// alphas epilogue. Block = 256 = 4 waves; wave = 1 node, lane = output element.
// sW uses a per-row quad rotation so ds_read_b128 spreads bank-quads.
__global__ __launch_bounds__(256) void gemm_h(const float* __restrict__ nodes,
                                              const float* __restrict__ W,
                                              const float* __restrict__ b,
                                              const float* __restrict__ attn_W,
                                              float* __restrict__ h,
                                              double* __restrict__ a_src,
                                              double* __restrict__ a_dst) {
    __shared__ float sW[HID * IN_DIM];     // rotated-quad layout
    __shared__ float sN[4 * IN_DIM];
    int t = threadIdx.x;
    // stage W (8192 floats = 2048 quads), rotated: logical (o,kq) -> o*128 + ((kq+o)&31)*4
    for (int i4 = t; i4 < HID * IN_DIM / 4; i4 += 256) {
        int o = i4 >> 5, kq = i4 & 31;
        float4 v = ((const float4*)W)[i4];
        *(float4*)&sW[o * IN_DIM + (((kq + o) & 31) << 2)] = v;
    }
    int node0 = blockIdx.x * 4;
    for (int i4 = t; i4 < 4 * IN_DIM / 4; i4 += 256) {
        int ln = i4 >> 5;
        int n = node0 + ln;
        float4 v = (n < N_NODES) ? ((const float4*)nodes)[(long long)n * (IN_DIM / 4) + (i4 & 31)]
                                 : make_float4(0.f, 0.f, 0.f, 0.f);
        *(float4*)&sN[i4 << 2] = v;
    }
    __syncthreads();
    int ln = t >> 6, o = t & 63;
    int n = node0 + ln;
    if (n >= N_NODES) return;
    double acc = (double)b[o];
    const float* wrow = &sW[o * IN_DIM];
    const float* nrow = &sN[ln * IN_DIM];
    #pragma unroll 8
    for (int kq = 0; kq < 32; ++kq) {
        float4 nv = *(const float4*)&nrow[kq << 2];                  // broadcast (same addr)
        float4 wv = *(const float4*)&wrow[((kq + o) & 31) << 2];     // rotated, spread banks
        acc += (double)wv.x * (double)nv.x;
        acc += (double)wv.y * (double)nv.y;
        acc += (double)wv.z * (double)nv.z;
        acc += (double)wv.w * (double)nv.w;
    }
    float hf = (float)acc;
    h[(long long)n * HID + o] = hf;
    // alphas epilogue from the ROUNDED f32 h (matches reference semantics)
    int hd = o >> 4, d = o & 15;
    double c0 = (double)hf * (double)attn_W[hd * AW_COLS + d];
    double c1 = (double)hf * (double)attn_W[hd * AW_COLS + OUT_DIM + d];
    #pragma unroll
    for (int k = 1; k <= 8; k <<= 1) {
        c0 += __shfl_xor(c0, k, 64);
        c1 += __shfl_xor(c1, k, 64);
    }
    if (d == 0) {
        a_src[n * N_HEADS + hd] = c0;
        a_dst[n * N_HEADS + hd] = c1;
    }
}

// Receiver histogram + block-reduced double sum of edges[sender] -> Ssum.
__global__ __launch_bounds__(256) void hist(const int* __restrict__ senders,
                                            const int* __restrict__ receivers,
                                            const float* __restrict__ edges,
                                            int* __restrict__ counts,
                                            double* __restrict__ Ssum) {
    __shared__ double red[256];
    int t = threadIdx.x;
    int e = blockIdx.x * 256 + t;
    double sp = 0.0;
    if (e < N_EDGES) {
        atomicAdd(&counts[receivers[e]], 1);
        sp = (double)edges[senders[e]];
    }
    red[t] = sp;
    __syncthreads();
    for (int off = 128; off > 0; off >>= 1) {
        if (t < off) red[t] += red[t + off];
        __syncthreads();
    }
    if (t == 0) atomicAdd(Ssum, red[0]);
}

// Single-block exclusive scan of counts -> offsets[N+1] + cursor rewrite.
// cursor may alias counts (read-before-write, one owner thread per index).
__global__ __launch_bounds__(SCAN_T) void scan_counts(const int* __restrict__ counts,
                                                      int* __restrict__ offsets,
                                                      int* cursor) {
    __shared__ int ssum[SCAN_T];
    int t = threadIdx.x;
    int base = t * SCAN_CH;
    int local = 0;
    for (int i = base; i < base + SCAN_CH && i < N_NODES; ++i) local += counts[i];
    ssum[t] = local;
    __syncthreads();
    for (int off = 1; off < SCAN_T; off <<= 1) {
        int v = 0;
        if (t >= off) v = ssum[t - off];
        __syncthreads();
        ssum[t] += v;
        __syncthreads();
    }
    int running = ssum[t] - local;
    for (int i = base; i < base + SCAN_CH && i < N_NODES; ++i) {
        int c = counts[i];
        offsets[i] = running;
        cursor[i] = running;
        running += c;
    }
    if (t == SCAN_T - 1) offsets[N_NODES] = ssum[SCAN_T - 1];
}

// Scatter sender ids into receiver-sorted order.
__global__ __launch_bounds__(256) void fill_srt(const int* __restrict__ senders,
                                                const int* __restrict__ receivers,
                                                int* __restrict__ cursor,
                                                int* __restrict__ srt_sender) {
    int e = blockIdx.x * 256 + threadIdx.x;
    if (e >= N_EDGES) return;
    int pos = atomicAdd(&cursor[receivers[e]], 1);
    srt_sender[pos] = senders[e];
}

// One wave per node. Lane = (head hd=lane>>4, slot q=lane&15); lane evaluates
// edges q+16j for ITS head only. Segmented 16-lane reductions for max/den.
// Near-one-hot softmax -> ballot-compressed accumulate loop.
__global__ __launch_bounds__(256) void node_fused(
    const float* __restrict__ h, const double* __restrict__ a_src,
    const double* __restrict__ a_dst, const float* __restrict__ edges,
    const int* __restrict__ srt_sender, const int* __restrict__ offsets,
    const float* __restrict__ attn_W, const float* __restrict__ attn_b,
    const double* __restrict__ Ssum, float* __restrict__ out) {
    int node = blockIdx.x * 4 + (threadIdx.x >> 6);
    int lane = threadIdx.x & 63;
    if (node >= N_NODES) return;
    int hd = lane >> 4, q = lane & 15;
    int start = offsets[node], end = offsets[node + 1];
    long long obase = (long long)node * HID + lane;
    if (start >= end) { out[obase] = 0.f; return; }

    double S = 4.0 * Ssum[0];                       // sent_e tiled over heads
    double w    = (double)attn_W[hd * AW_COLS + 2 * OUT_DIM];
    double bb   = (double)attn_b[hd];
    double adst = a_dst[node * N_HEADS + hd];
    float m_run = -INFINITY;
    float den = 0.f, acc = 0.f;

    for (int cbase = start; cbase < end; cbase += 64) {
        int cd = end - cbase; if (cd > 64) cd = 64;
        float y[4], ev[4];
        #pragma unroll
        for (int j = 0; j < 4; ++j) {
            int ei = q + 16 * j;
            y[j] = -INFINITY;
            if (ei < cd) {
                int s = srt_sender[cbase + ei];
                double se = (double)edges[s];
                double as = a_src[(long long)s * N_HEADS + hd];
                double yy = as + adst + se * w + bb;
                yy = yy > 0.0 ? yy : 0.01 * yy;     // leaky (fp64, then round)
                y[j] = (float)yy;
            }
        }
        // per-head (16-lane segment) chunk max
        float mv = fmaxf(fmaxf(y[0], y[1]), fmaxf(y[2], y[3]));
        #pragma unroll
        for (int k = 1; k <= 8; k <<= 1)
            mv = fmaxf(mv, __shfl_xor(mv, k, 64));
        float mn = fmaxf(m_run, mv);
        float sc = (m_run == -INFINITY) ? 0.f
                 : __expf((float)(S * ((double)m_run - (double)mn)));
        den *= sc; acc *= sc; m_run = mn;
        // ev per slot (fp64 arg, fp32 exp) + segmented den sum
        float dsum = 0.f;
        #pragma unroll
        for (int j = 0; j < 4; ++j) {
            ev[j] = (y[j] == -INFINITY) ? 0.f
                  : __expf((float)(S * ((double)y[j] - (double)m_run)));
            dsum += ev[j];
        }
        #pragma unroll
        for (int k = 1; k <= 8; k <<= 1)
            dsum += __shfl_xor(dsum, k, 64);
        den += dsum;
        // accumulate only surviving edges (exact skip of ev==0)
        #pragma unroll
        for (int j = 0; j < 4; ++j) {
            unsigned long long mk = __ballot(ev[j] != 0.f);
            unsigned um = (unsigned)((mk | (mk >> 16) | (mk >> 32) | (mk >> 48)) & 0xFFFFull);
            while (um) {
                int qq = __builtin_ctz(um);
                um &= um - 1;
                float evv = __shfl(ev[j], (lane & 48) | qq, 64);  // own head's ev
                int sj = srt_sender[cbase + 16 * j + qq];         // uniform -> scalar
                if (evv != 0.f)
                    acc = fmaf(evv, h[(long long)sj * HID + lane], acc);
            }
        }
    }
    float r = (den > 0.f) ? acc / den : 0.f;
    out[obase] = r > 0.f ? r : 0.01f * r;
}

static inline char* ws_take(char*& p, size_t bytes) {
    char* cur = p;
    p += (bytes + 255) & ~(size_t)255;   // keep every buffer 256B-aligned
    return cur;
}

extern "C" void kernel_launch(void* const* d_in, const int* in_sizes, int n_in,
                              void* d_out, int out_size, void* d_ws, size_t ws_size,
                              hipStream_t stream) {
    const float* nodes     = (const float*)d_in[0];
    const float* edges     = (const float*)d_in[1];
    const int*   senders   = (const int*)d_in[2];
    const int*   receivers = (const int*)d_in[3];
    const float* W         = (const float*)d_in[4];
    const float* b         = (const float*)d_in[5];
    const float* attn_W    = (const float*)d_in[6];
    const float* attn_b    = (const float*)d_in[7];
    float* out = (float*)d_out;

    char* p = (char*)d_ws;
    float*  h          = (float*)ws_take(p, sizeof(float) * N_NODES * HID);
    double* a_src      = (double*)ws_take(p, sizeof(double) * N_NODES * N_HEADS);
    double* a_dst      = (double*)ws_take(p, sizeof(double) * N_NODES * N_HEADS);
    int*    counts     = (int*)ws_take(p, sizeof(int) * N_NODES);   // reused as cursor
    int*    offsets    = (int*)ws_take(p, sizeof(int) * (N_NODES + 1));
    int*    srt_sender = (int*)ws_take(p, sizeof(int) * (size_t)N_EDGES);
    double* Ssum       = (double*)ws_take(p, sizeof(double));
    int* cursor = counts;

    hipMemsetAsync(counts, 0, sizeof(int) * N_NODES, stream);
    hipMemsetAsync(Ssum, 0, sizeof(double), stream);

    gemm_h<<<(N_NODES + 3) / 4, 256, 0, stream>>>(nodes, W, b, attn_W, h, a_src, a_dst);
    hist<<<(N_EDGES + 255) / 256, 256, 0, stream>>>(senders, receivers, edges, counts, Ssum);
    scan_counts<<<1, SCAN_T, 0, stream>>>(counts, offsets, cursor);
    fill_srt<<<(N_EDGES + 255) / 256, 256, 0, stream>>>(senders, receivers, cursor, srt_sender);
    node_fused<<<(N_NODES + 3) / 4, 256, 0, stream>>>(
        h, a_src, a_dst, edges, srt_sender, offsets, attn_W, attn_b, Ssum, out);
}

// Round 6
// 295.925 us; speedup vs baseline: 3.5599x; 1.3270x over previous
//
#include <hip/hip_runtime.h>
#include <math.h>

#define N_NODES 50000
#define N_EDGES 800000
#define IN_DIM 128
#define OUT_DIM 16
#define N_HEADS 4
#define HID 64            // N_HEADS*OUT_DIM
#define AW_COLS 33        // 2*OUT_DIM+1
#define NBLK ((N_NODES + 255) / 256)   // 196

// h = nodes @ W.T + b (fp64 accumulate, SAME k-order as prior rounds) fused with
// alphas epilogue. Block = 256 = 4 waves; wave = 1 node, lane = output element.
// sW uses a per-row quad rotation so ds_read_b128 spreads bank-quads.
__global__ __launch_bounds__(256) void gemm_h(const float* __restrict__ nodes,
                                              const float* __restrict__ W,
                                              const float* __restrict__ b,
                                              const float* __restrict__ attn_W,
                                              float* __restrict__ h,
                                              double* __restrict__ a_src,
                                              double* __restrict__ a_dst) {
    __shared__ float sW[HID * IN_DIM];     // rotated-quad layout
    __shared__ float sN[4 * IN_DIM];
    int t = threadIdx.x;
    for (int i4 = t; i4 < HID * IN_DIM / 4; i4 += 256) {
        int o = i4 >> 5, kq = i4 & 31;
        float4 v = ((const float4*)W)[i4];
        *(float4*)&sW[o * IN_DIM + (((kq + o) & 31) << 2)] = v;
    }
    int node0 = blockIdx.x * 4;
    for (int i4 = t; i4 < 4 * IN_DIM / 4; i4 += 256) {
        int ln = i4 >> 5;
        int n = node0 + ln;
        float4 v = (n < N_NODES) ? ((const float4*)nodes)[(long long)n * (IN_DIM / 4) + (i4 & 31)]
                                 : make_float4(0.f, 0.f, 0.f, 0.f);
        *(float4*)&sN[i4 << 2] = v;
    }
    __syncthreads();
    int ln = t >> 6, o = t & 63;
    int n = node0 + ln;
    if (n >= N_NODES) return;
    double acc = (double)b[o];
    const float* wrow = &sW[o * IN_DIM];
    const float* nrow = &sN[ln * IN_DIM];
    #pragma unroll 8
    for (int kq = 0; kq < 32; ++kq) {
        float4 nv = *(const float4*)&nrow[kq << 2];                  // broadcast (same addr)
        float4 wv = *(const float4*)&wrow[((kq + o) & 31) << 2];     // rotated, spread banks
        acc += (double)wv.x * (double)nv.x;
        acc += (double)wv.y * (double)nv.y;
        acc += (double)wv.z * (double)nv.z;
        acc += (double)wv.w * (double)nv.w;
    }
    float hf = (float)acc;
    h[(long long)n * HID + o] = hf;
    // alphas epilogue from the ROUNDED f32 h (matches reference semantics)
    int hd = o >> 4, d = o & 15;
    double c0 = (double)hf * (double)attn_W[hd * AW_COLS + d];
    double c1 = (double)hf * (double)attn_W[hd * AW_COLS + OUT_DIM + d];
    #pragma unroll
    for (int k = 1; k <= 8; k <<= 1) {
        c0 += __shfl_xor(c0, k, 64);
        c1 += __shfl_xor(c1, k, 64);
    }
    if (d == 0) {
        a_src[n * N_HEADS + hd] = c0;
        a_dst[n * N_HEADS + hd] = c1;
    }
}

// Receiver histogram + block-reduced double sum of edges[sender] -> Ssum.
__global__ __launch_bounds__(256) void hist(const int* __restrict__ senders,
                                            const int* __restrict__ receivers,
                                            const float* __restrict__ edges,
                                            int* __restrict__ counts,
                                            double* __restrict__ Ssum) {
    __shared__ double red[256];
    int t = threadIdx.x;
    int e = blockIdx.x * 256 + t;
    double sp = 0.0;
    if (e < N_EDGES) {
        atomicAdd(&counts[receivers[e]], 1);
        sp = (double)edges[senders[e]];
    }
    red[t] = sp;
    __syncthreads();
    for (int off = 128; off > 0; off >>= 1) {
        if (t < off) red[t] += red[t + off];
        __syncthreads();
    }
    if (t == 0) atomicAdd(Ssum, red[0]);
}

// ---- 3-phase multi-block exclusive scan of counts -> offsets/cursor ----
__global__ __launch_bounds__(256) void partial_sums(const int* __restrict__ counts,
                                                    int* __restrict__ partials) {
    __shared__ int red[256];
    int t = threadIdx.x;
    int i = blockIdx.x * 256 + t;
    red[t] = (i < N_NODES) ? counts[i] : 0;
    __syncthreads();
    for (int off = 128; off > 0; off >>= 1) {
        if (t < off) red[t] += red[t + off];
        __syncthreads();
    }
    if (t == 0) partials[blockIdx.x] = red[0];
}

__global__ __launch_bounds__(256) void scan_partials(int* __restrict__ partials) {
    __shared__ int s[256];
    int t = threadIdx.x;
    int v = (t < NBLK) ? partials[t] : 0;
    s[t] = v;
    __syncthreads();
    for (int off = 1; off < 256; off <<= 1) {
        int u = (t >= off) ? s[t - off] : 0;
        __syncthreads();
        s[t] += u;
        __syncthreads();
    }
    if (t < NBLK) partials[t] = s[t] - v;   // exclusive block offsets
}

__global__ __launch_bounds__(256) void scan_final(const int* __restrict__ counts,
                                                  const int* __restrict__ partials,
                                                  int* __restrict__ offsets,
                                                  int* __restrict__ cursor) {
    __shared__ int s[256];
    int t = threadIdx.x;
    int i = blockIdx.x * 256 + t;
    int c = (i < N_NODES) ? counts[i] : 0;
    s[t] = c;
    __syncthreads();
    for (int off = 1; off < 256; off <<= 1) {
        int u = (t >= off) ? s[t - off] : 0;
        __syncthreads();
        s[t] += u;
        __syncthreads();
    }
    if (i < N_NODES) {
        int pos = partials[blockIdx.x] + s[t] - c;   // exclusive prefix
        offsets[i] = pos;
        cursor[i] = pos;
    }
    if (i == 0) offsets[N_NODES] = N_EDGES;   // total is exactly N_EDGES
}

// Scatter sender ids into receiver-sorted order.
__global__ __launch_bounds__(256) void fill_srt(const int* __restrict__ senders,
                                                const int* __restrict__ receivers,
                                                int* __restrict__ cursor,
                                                int* __restrict__ srt_sender) {
    int e = blockIdx.x * 256 + threadIdx.x;
    if (e >= N_EDGES) return;
    int pos = atomicAdd(&cursor[receivers[e]], 1);
    srt_sender[pos] = senders[e];
}

// One wave per node. Lane = (head hd=lane>>4, slot q=lane&15); lane evaluates
// edges q+16j for ITS head only. Segmented 16-lane reductions for max/den.
// Near-one-hot softmax -> ballot-compressed accumulate loop.
__global__ __launch_bounds__(256) void node_fused(
    const float* __restrict__ h, const double* __restrict__ a_src,
    const double* __restrict__ a_dst, const float* __restrict__ edges,
    const int* __restrict__ srt_sender, const int* __restrict__ offsets,
    const float* __restrict__ attn_W, const float* __restrict__ attn_b,
    const double* __restrict__ Ssum, float* __restrict__ out) {
    int node = blockIdx.x * 4 + (threadIdx.x >> 6);
    int lane = threadIdx.x & 63;
    if (node >= N_NODES) return;
    int hd = lane >> 4, q = lane & 15;
    int start = offsets[node], end = offsets[node + 1];
    long long obase = (long long)node * HID + lane;
    if (start >= end) { out[obase] = 0.f; return; }

    double S = 4.0 * Ssum[0];                       // sent_e tiled over heads
    double w    = (double)attn_W[hd * AW_COLS + 2 * OUT_DIM];
    double bb   = (double)attn_b[hd];
    double adst = a_dst[node * N_HEADS + hd];
    float m_run = -INFINITY;
    float den = 0.f, acc = 0.f;

    for (int cbase = start; cbase < end; cbase += 64) {
        int cd = end - cbase; if (cd > 64) cd = 64;
        float y[4], ev[4];
        #pragma unroll
        for (int j = 0; j < 4; ++j) {
            int ei = q + 16 * j;
            y[j] = -INFINITY;
            if (ei < cd) {
                int s = srt_sender[cbase + ei];
                double se = (double)edges[s];
                double as = a_src[(long long)s * N_HEADS + hd];
                double yy = as + adst + se * w + bb;
                yy = yy > 0.0 ? yy : 0.01 * yy;     // leaky (fp64, then round)
                y[j] = (float)yy;
            }
        }
        // per-head (16-lane segment) chunk max
        float mv = fmaxf(fmaxf(y[0], y[1]), fmaxf(y[2], y[3]));
        #pragma unroll
        for (int k = 1; k <= 8; k <<= 1)
            mv = fmaxf(mv, __shfl_xor(mv, k, 64));
        float mn = fmaxf(m_run, mv);
        float sc = (m_run == -INFINITY) ? 0.f
                 : __expf((float)(S * ((double)m_run - (double)mn)));
        den *= sc; acc *= sc; m_run = mn;
        // ev per slot (fp64 arg, fp32 exp) + segmented den sum
        float dsum = 0.f;
        #pragma unroll
        for (int j = 0; j < 4; ++j) {
            ev[j] = (y[j] == -INFINITY) ? 0.f
                  : __expf((float)(S * ((double)y[j] - (double)m_run)));
            dsum += ev[j];
        }
        #pragma unroll
        for (int k = 1; k <= 8; k <<= 1)
            dsum += __shfl_xor(dsum, k, 64);
        den += dsum;
        // accumulate only surviving edges (exact skip of ev==0)
        #pragma unroll
        for (int j = 0; j < 4; ++j) {
            unsigned long long mk = __ballot(ev[j] != 0.f);
            unsigned um = (unsigned)((mk | (mk >> 16) | (mk >> 32) | (mk >> 48)) & 0xFFFFull);
            while (um) {
                int qq = __builtin_ctz(um);
                um &= um - 1;
                float evv = __shfl(ev[j], (lane & 48) | qq, 64);  // own head's ev
                int sj = srt_sender[cbase + 16 * j + qq];         // uniform -> scalar
                if (evv != 0.f)
                    acc = fmaf(evv, h[(long long)sj * HID + lane], acc);
            }
        }
    }
    float r = (den > 0.f) ? acc / den : 0.f;
    out[obase] = r > 0.f ? r : 0.01f * r;
}

static inline char* ws_take(char*& p, size_t bytes) {
    char* cur = p;
    p += (bytes + 255) & ~(size_t)255;   // keep every buffer 256B-aligned
    return cur;
}

extern "C" void kernel_launch(void* const* d_in, const int* in_sizes, int n_in,
                              void* d_out, int out_size, void* d_ws, size_t ws_size,
                              hipStream_t stream) {
    const float* nodes     = (const float*)d_in[0];
    const float* edges     = (const float*)d_in[1];
    const int*   senders   = (const int*)d_in[2];
    const int*   receivers = (const int*)d_in[3];
    const float* W         = (const float*)d_in[4];
    const float* b         = (const float*)d_in[5];
    const float* attn_W    = (const float*)d_in[6];
    const float* attn_b    = (const float*)d_in[7];
    float* out = (float*)d_out;

    char* p = (char*)d_ws;
    float*  h          = (float*)ws_take(p, sizeof(float) * N_NODES * HID);
    double* a_src      = (double*)ws_take(p, sizeof(double) * N_NODES * N_HEADS);
    double* a_dst      = (double*)ws_take(p, sizeof(double) * N_NODES * N_HEADS);
    int*    counts     = (int*)ws_take(p, sizeof(int) * N_NODES);
    int*    offsets    = (int*)ws_take(p, sizeof(int) * (N_NODES + 1));
    int*    cursor     = (int*)ws_take(p, sizeof(int) * N_NODES);
    int*    partials   = (int*)ws_take(p, sizeof(int) * NBLK);
    int*    srt_sender = (int*)ws_take(p, sizeof(int) * (size_t)N_EDGES);
    double* Ssum       = (double*)ws_take(p, sizeof(double));

    hipMemsetAsync(counts, 0, sizeof(int) * N_NODES, stream);
    hipMemsetAsync(Ssum, 0, sizeof(double), stream);

    gemm_h<<<(N_NODES + 3) / 4, 256, 0, stream>>>(nodes, W, b, attn_W, h, a_src, a_dst);
    hist<<<(N_EDGES + 255) / 256, 256, 0, stream>>>(senders, receivers, edges, counts, Ssum);
    partial_sums<<<NBLK, 256, 0, stream>>>(counts, partials);
    scan_partials<<<1, 256, 0, stream>>>(partials);
    scan_final<<<NBLK, 256, 0, stream>>>(counts, partials, offsets, cursor);
    fill_srt<<<(N_EDGES + 255) / 256, 256, 0, stream>>>(senders, receivers, cursor, srt_sender);
    node_fused<<<(N_NODES + 3) / 4, 256, 0, stream>>>(
        h, a_src, a_dst, edges, srt_sender, offsets, attn_W, attn_b, Ssum, out);
}